// Round 1
// baseline (1163.940 us; speedup 1.0000x reference)
//
#include <hip/hip_runtime.h>
#include <stdint.h>

#define NTOK 1024   // H*W
#define NCH  2048   // C
#define MID  128
#define P2   256    // 2*MID (Wq stacked on Wk)
#define NB   32

typedef __attribute__((ext_vector_type(4))) float f32x4;
typedef __attribute__((ext_vector_type(8))) short s16x8;

__device__ __forceinline__ unsigned short f2bf(float x) {
    union { float f; unsigned u; } v; v.f = x;
    unsigned u = v.u;
    return (unsigned short)((u + 0x7FFFu + ((u >> 16) & 1u)) >> 16);
}
__device__ __forceinline__ float bf2f(unsigned short h) {
    union { unsigned u; float f; } v; v.u = ((unsigned)h) << 16;
    return v.f;
}

// ---------------- K0: split Wq||Wk into hi/lo bf16 [256][2048] ----------------
__global__ __launch_bounds__(256) void k_split_w(
    const float* __restrict__ Wq, const float* __restrict__ Wk,
    unsigned short* __restrict__ Wh, unsigned short* __restrict__ Wl)
{
    size_t idx = (size_t)blockIdx.x * 256 + threadIdx.x;   // one float4 each
    size_t e4 = idx * 4;                                   // 512 blocks * 256 * 4 = 524288
    int p = (int)(e4 >> 11);
    int c = (int)(e4 & 2047);
    const float* src = (p < MID) ? (Wq + (size_t)p * NCH + c)
                                 : (Wk + (size_t)(p - MID) * NCH + c);
    float4 v = *(const float4*)src;
    float a[4] = { v.x, v.y, v.z, v.w };
    union { unsigned short us[4]; uint2 u; } h, l;
#pragma unroll
    for (int j = 0; j < 4; ++j) {
        unsigned short hh = f2bf(a[j]);
        h.us[j] = hh;
        l.us[j] = f2bf(a[j] - bf2f(hh));
    }
    *(uint2*)(Wh + e4) = h.u;
    *(uint2*)(Wl + e4) = l.u;
}

// ------- K0b: feat[b][c][i] -> featT[slot][i][c] as hi/lo bf16 (64x64 tiles) -------
__global__ __launch_bounds__(256) void k_transpose_split(
    const float* __restrict__ feat,
    unsigned short* __restrict__ Th, unsigned short* __restrict__ Tl, int bb0)
{
    __shared__ float tile[64][65];
    int s = blockIdx.z;
    int b = bb0 + s;
    int i0 = blockIdx.x * 64;
    int c0 = blockIdx.y * 64;
    int t = threadIdx.x;
    const float* src = feat + ((size_t)b * NCH + c0) * NTOK + i0;
#pragma unroll
    for (int k = 0; k < 4; ++k) {
        int idx = t + k * 256;
        int r = idx >> 4, c4 = (idx & 15) * 4;
        float4 v = *(const float4*)(src + (size_t)r * NTOK + c4);
        tile[r][c4 + 0] = v.x; tile[r][c4 + 1] = v.y;
        tile[r][c4 + 2] = v.z; tile[r][c4 + 3] = v.w;
    }
    __syncthreads();
    size_t obase = ((size_t)s * NTOK + i0) * NCH + c0;
#pragma unroll
    for (int k = 0; k < 2; ++k) {
        int idx = t + k * 256;
        int ii = idx >> 3, c8 = (idx & 7) * 8;
        union { unsigned short us[8]; uint4 v; } uh, ul;
#pragma unroll
        for (int j = 0; j < 8; ++j) {
            float x = tile[c8 + j][ii];
            unsigned short hh = f2bf(x);
            uh.us[j] = hh;
            ul.us[j] = f2bf(x - bf2f(hh));
        }
        *(uint4*)(Th + obase + (size_t)ii * NCH + c8) = uh.v;
        *(uint4*)(Tl + obase + (size_t)ii * NCH + c8) = ul.v;
    }
}

// ---- K1: fT[i][p] = sum_c featT[i][c]*W[p][c], split 3-MFMA. BM=128 BN=64 BK=64 ----
#define K1_LDK 72
__global__ __launch_bounds__(256) void k_proj(
    const unsigned short* __restrict__ Th, const unsigned short* __restrict__ Tl,
    const unsigned short* __restrict__ Wh, const unsigned short* __restrict__ Wl,
    unsigned short* __restrict__ Fh, unsigned short* __restrict__ Fl, int bb0)
{
    __shared__ unsigned short Ah[128 * K1_LDK], Al[128 * K1_LDK];
    __shared__ unsigned short Bh[64 * K1_LDK],  Bl[64 * K1_LDK];
    int s  = blockIdx.y >> 3;            // slot within chunk
    int i0 = (blockIdx.y & 7) * 128;
    int p0 = blockIdx.x * 64;
    int t = threadIdx.x, lane = t & 63, w = t >> 6;
    int wr = (w >> 1) * 64, wc = (w & 1) * 32;
    int la = lane & 15, lb = (lane >> 4) * 8;
    f32x4 acc[4][2];
#pragma unroll
    for (int mf = 0; mf < 4; ++mf)
#pragma unroll
        for (int nf = 0; nf < 2; ++nf) acc[mf][nf] = (f32x4)0.f;

    size_t abase = ((size_t)s * NTOK + i0) * NCH;
    size_t bbase = (size_t)p0 * NCH;
    for (int kt = 0; kt < NCH / 64; ++kt) {
        int k0 = kt * 64;
        __syncthreads();
#pragma unroll
        for (int q = 0; q < 4; ++q) {                 // A: 128 rows x 8 chunks
            int idx = t + q * 256;
            int r = idx >> 3, c8 = (idx & 7) * 8;
            *(uint4*)&Ah[r * K1_LDK + c8] = *(const uint4*)(Th + abase + (size_t)r * NCH + k0 + c8);
            *(uint4*)&Al[r * K1_LDK + c8] = *(const uint4*)(Tl + abase + (size_t)r * NCH + k0 + c8);
        }
#pragma unroll
        for (int q = 0; q < 2; ++q) {                 // B: 64 rows x 8 chunks
            int idx = t + q * 256;
            int r = idx >> 3, c8 = (idx & 7) * 8;
            *(uint4*)&Bh[r * K1_LDK + c8] = *(const uint4*)(Wh + bbase + (size_t)r * NCH + k0 + c8);
            *(uint4*)&Bl[r * K1_LDK + c8] = *(const uint4*)(Wl + bbase + (size_t)r * NCH + k0 + c8);
        }
        __syncthreads();
#pragma unroll
        for (int kk = 0; kk < 2; ++kk) {
            int kofs = kk * 32 + lb;
            s16x8 bh[2], bl[2];
#pragma unroll
            for (int nf = 0; nf < 2; ++nf) {
                bh[nf] = *(s16x8*)&Bh[(wc + nf * 16 + la) * K1_LDK + kofs];
                bl[nf] = *(s16x8*)&Bl[(wc + nf * 16 + la) * K1_LDK + kofs];
            }
#pragma unroll
            for (int mf = 0; mf < 4; ++mf) {
                s16x8 ah = *(s16x8*)&Ah[(wr + mf * 16 + la) * K1_LDK + kofs];
                s16x8 al = *(s16x8*)&Al[(wr + mf * 16 + la) * K1_LDK + kofs];
#pragma unroll
                for (int nf = 0; nf < 2; ++nf) {
                    acc[mf][nf] = __builtin_amdgcn_mfma_f32_16x16x32_bf16(ah, bh[nf], acc[mf][nf], 0, 0, 0);
                    acc[mf][nf] = __builtin_amdgcn_mfma_f32_16x16x32_bf16(al, bh[nf], acc[mf][nf], 0, 0, 0);
                    acc[mf][nf] = __builtin_amdgcn_mfma_f32_16x16x32_bf16(ah, bl[nf], acc[mf][nf], 0, 0, 0);
                }
            }
        }
    }
    int babs = bb0 + s;
#pragma unroll
    for (int mf = 0; mf < 4; ++mf)
#pragma unroll
        for (int nf = 0; nf < 2; ++nf)
#pragma unroll
            for (int r = 0; r < 4; ++r) {
                int i = i0 + wr + mf * 16 + ((lane >> 4) * 4) + r;
                int p = p0 + wc + nf * 16 + la;
                float x = acc[mf][nf][r];
                unsigned short hh = f2bf(x);
                size_t o = ((size_t)babs * NTOK + i) * P2 + p;
                Fh[o] = hh;
                Fl[o] = f2bf(x - bf2f(hh));
            }
}

// ---- K2: logits (split 3-MFMA, K=128) + fused softmax + P bf16. 32 rows/block ----
__global__ __launch_bounds__(512) void k_attn(
    const unsigned short* __restrict__ Fh, const unsigned short* __restrict__ Fl,
    unsigned short* __restrict__ Pm)
{
    __shared__ float lred[8 * 32 + 32];
    int s = blockIdx.y;                    // absolute batch
    int i0 = blockIdx.x * 32;
    int t = threadIdx.x, lane = t & 63, w = t >> 6;
    int la = lane & 15, lg = lane >> 4;
    int jw = w * 128;
    size_t fbase = (size_t)s * NTOK * P2;
    f32x4 acc[2][8];
#pragma unroll
    for (int mf = 0; mf < 2; ++mf)
#pragma unroll
        for (int nf = 0; nf < 8; ++nf) acc[mf][nf] = (f32x4)0.f;

#pragma unroll
    for (int ks = 0; ks < 4; ++ks) {
        int kofs = ks * 32 + lg * 8;
        s16x8 ah[2], al[2];
#pragma unroll
        for (int mf = 0; mf < 2; ++mf) {
            size_t ao = fbase + (size_t)(i0 + mf * 16 + la) * P2 + kofs;
            ah[mf] = *(const s16x8*)(Fh + ao);
            al[mf] = *(const s16x8*)(Fl + ao);
        }
#pragma unroll
        for (int nf = 0; nf < 8; ++nf) {
            size_t bo = fbase + (size_t)(jw + nf * 16 + la) * P2 + MID + kofs;
            s16x8 bh = *(const s16x8*)(Fh + bo);
            s16x8 bl = *(const s16x8*)(Fl + bo);
#pragma unroll
            for (int mf = 0; mf < 2; ++mf) {
                acc[mf][nf] = __builtin_amdgcn_mfma_f32_16x16x32_bf16(ah[mf], bh, acc[mf][nf], 0, 0, 0);
                acc[mf][nf] = __builtin_amdgcn_mfma_f32_16x16x32_bf16(al[mf], bh, acc[mf][nf], 0, 0, 0);
                acc[mf][nf] = __builtin_amdgcn_mfma_f32_16x16x32_bf16(ah[mf], bl, acc[mf][nf], 0, 0, 0);
            }
        }
    }
    // ---- row max (rows = i0 + mf*16 + lg*4 + r; cols per lane: la + 16*nf in wave stripe)
    float mx[2][4];
#pragma unroll
    for (int mf = 0; mf < 2; ++mf)
#pragma unroll
        for (int r = 0; r < 4; ++r) {
            float m = acc[mf][0][r];
#pragma unroll
            for (int nf = 1; nf < 8; ++nf) m = fmaxf(m, acc[mf][nf][r]);
            mx[mf][r] = m;
        }
#pragma unroll
    for (int off = 1; off < 16; off <<= 1)
#pragma unroll
        for (int mf = 0; mf < 2; ++mf)
#pragma unroll
            for (int r = 0; r < 4; ++r)
                mx[mf][r] = fmaxf(mx[mf][r], __shfl_xor(mx[mf][r], off, 64));
    if (la == 0) {
#pragma unroll
        for (int mf = 0; mf < 2; ++mf)
#pragma unroll
            for (int r = 0; r < 4; ++r)
                lred[w * 32 + mf * 16 + lg * 4 + r] = mx[mf][r];
    }
    __syncthreads();
    if (t < 32) {
        float m = lred[t];
#pragma unroll
        for (int ww = 1; ww < 8; ++ww) m = fmaxf(m, lred[ww * 32 + t]);
        lred[256 + t] = m;
    }
    __syncthreads();
    float rmx[2][4], sm[2][4];
#pragma unroll
    for (int mf = 0; mf < 2; ++mf)
#pragma unroll
        for (int r = 0; r < 4; ++r) {
            rmx[mf][r] = lred[256 + mf * 16 + lg * 4 + r];
            sm[mf][r] = 0.f;
        }
#pragma unroll
    for (int mf = 0; mf < 2; ++mf)
#pragma unroll
        for (int nf = 0; nf < 8; ++nf)
#pragma unroll
            for (int r = 0; r < 4; ++r) {
                float p = __expf(acc[mf][nf][r] - rmx[mf][r]);
                acc[mf][nf][r] = p;
                sm[mf][r] += p;
            }
#pragma unroll
    for (int off = 1; off < 16; off <<= 1)
#pragma unroll
        for (int mf = 0; mf < 2; ++mf)
#pragma unroll
            for (int r = 0; r < 4; ++r)
                sm[mf][r] += __shfl_xor(sm[mf][r], off, 64);
    __syncthreads();   // ensure rowmax reads done before overwriting partials
    if (la == 0) {
#pragma unroll
        for (int mf = 0; mf < 2; ++mf)
#pragma unroll
            for (int r = 0; r < 4; ++r)
                lred[w * 32 + mf * 16 + lg * 4 + r] = sm[mf][r];
    }
    __syncthreads();
    if (t < 32) {
        float ssum = 0.f;
#pragma unroll
        for (int ww = 0; ww < 8; ++ww) ssum += lred[ww * 32 + t];
        lred[256 + t] = 1.f / ssum;
    }
    __syncthreads();
#pragma unroll
    for (int mf = 0; mf < 2; ++mf)
#pragma unroll
        for (int r = 0; r < 4; ++r) {
            float inv = lred[256 + mf * 16 + lg * 4 + r];
            int row = i0 + mf * 16 + lg * 4 + r;
#pragma unroll
            for (int nf = 0; nf < 8; ++nf) {
                unsigned short v = f2bf(acc[mf][nf][r] * inv);
                Pm[((size_t)s * NTOK + row) * NTOK + jw + nf * 16 + la] = v;
            }
        }
}

// ---- K3: out[c][i] = alpha * sum_j cam[c][j]*P[i][j] + cam[c][i]. 128x128x64 ----
#define K3_LDK 72
__global__ __launch_bounds__(256) void k_pv(
    const float* __restrict__ cam, const unsigned short* __restrict__ Pm,
    const float* __restrict__ alphap, float* __restrict__ out)
{
    __shared__ unsigned short Asm[128 * K3_LDK], Bsm[128 * K3_LDK];
    int b = blockIdx.z;
    int c0 = blockIdx.y * 128, i0 = blockIdx.x * 128;
    int t = threadIdx.x, lane = t & 63, w = t >> 6;
    int wr = (w >> 1) * 64, wc = (w & 1) * 64;
    int la = lane & 15, lb = (lane >> 4) * 8;
    f32x4 acc[4][4];
#pragma unroll
    for (int mf = 0; mf < 4; ++mf)
#pragma unroll
        for (int nf = 0; nf < 4; ++nf) acc[mf][nf] = (f32x4)0.f;

    const float* camb = cam + (size_t)b * NCH * NTOK;
    for (int kt = 0; kt < NTOK / 64; ++kt) {
        int k0 = kt * 64;
        __syncthreads();
#pragma unroll
        for (int q = 0; q < 8; ++q) {     // A: cam fp32 -> bf16, 128 rows x 16 float4
            int idx = t + q * 256;
            int r = idx >> 4, c4 = (idx & 15) * 4;
            float4 v = *(const float4*)(camb + (size_t)(c0 + r) * NTOK + k0 + c4);
            union { unsigned short us[4]; unsigned long long u; } pk;
            pk.us[0] = f2bf(v.x); pk.us[1] = f2bf(v.y);
            pk.us[2] = f2bf(v.z); pk.us[3] = f2bf(v.w);
            *(unsigned long long*)&Asm[r * K3_LDK + c4] = pk.u;
        }
#pragma unroll
        for (int q = 0; q < 4; ++q) {     // B: P bf16, 128 rows x 8 chunks
            int idx = t + q * 256;
            int r = idx >> 3, c8 = (idx & 7) * 8;
            *(uint4*)&Bsm[r * K3_LDK + c8] =
                *(const uint4*)(Pm + ((size_t)b * NTOK + i0 + r) * NTOK + k0 + c8);
        }
        __syncthreads();
#pragma unroll
        for (int kk = 0; kk < 2; ++kk) {
            int kofs = kk * 32 + lb;
            s16x8 bfr[4];
#pragma unroll
            for (int nf = 0; nf < 4; ++nf)
                bfr[nf] = *(s16x8*)&Bsm[(wc + nf * 16 + la) * K3_LDK + kofs];
#pragma unroll
            for (int mf = 0; mf < 4; ++mf) {
                s16x8 a = *(s16x8*)&Asm[(wr + mf * 16 + la) * K3_LDK + kofs];
#pragma unroll
                for (int nf = 0; nf < 4; ++nf)
                    acc[mf][nf] = __builtin_amdgcn_mfma_f32_16x16x32_bf16(a, bfr[nf], acc[mf][nf], 0, 0, 0);
            }
        }
    }
    float alpha = *alphap;
    float* outb = out + (size_t)b * NCH * NTOK;
#pragma unroll
    for (int mf = 0; mf < 4; ++mf)
#pragma unroll
        for (int nf = 0; nf < 4; ++nf)
#pragma unroll
            for (int r = 0; r < 4; ++r) {
                int c = c0 + wr + mf * 16 + (lane >> 4) * 4 + r;
                int i = i0 + wc + nf * 16 + la;
                size_t o = (size_t)c * NTOK + i;
                outb[o] = alpha * acc[mf][nf][r] + camb[o];
            }
}

extern "C" void kernel_launch(void* const* d_in, const int* in_sizes, int n_in,
                              void* d_out, int out_size, void* d_ws, size_t ws_size,
                              hipStream_t stream) {
    const float* feat   = (const float*)d_in[0];
    const float* cam    = (const float*)d_in[1];
    const float* Wq     = (const float*)d_in[2];
    const float* Wk     = (const float*)d_in[3];
    const float* alphap = (const float*)d_in[4];
    float* out = (float*)d_out;

    const size_t MB = 1ull << 20;
    // chunk size for featT staging: need 2MB (W) + 96MB (F+P, all batches) + G*8MB (featT)
    int G = 32;
    while (G > 1 && (2 * MB + 96 * MB + (size_t)G * 8 * MB) > ws_size) G >>= 1;

    unsigned short* Wh = (unsigned short*)d_ws;
    unsigned short* Wl = Wh + (size_t)P2 * NCH;                       // +1MB
    unsigned short* Th = (unsigned short*)((char*)d_ws + 2 * MB);     // featT hi: G*4MB
    unsigned short* Tl = Th + (size_t)G * NTOK * NCH;                 // featT lo: G*4MB
    unsigned short* Fh = Tl + (size_t)G * NTOK * NCH;                 // f hi: 16MB (all batches)
    unsigned short* Fl = Fh + (size_t)NB * NTOK * P2;                 // f lo: 16MB
    unsigned short* Pm = Fl + (size_t)NB * NTOK * P2;                 // P: 64MB

    k_split_w<<<dim3(512), dim3(256), 0, stream>>>(Wq, Wk, Wh, Wl);
    for (int bb0 = 0; bb0 < NB; bb0 += G) {
        int g = (NB - bb0 < G) ? (NB - bb0) : G;
        k_transpose_split<<<dim3(16, 32, g), dim3(256), 0, stream>>>(feat, Th, Tl, bb0);
        k_proj<<<dim3(4, 8 * g), dim3(256), 0, stream>>>(Th, Tl, Wh, Wl, Fh, Fl, bb0);
    }
    k_attn<<<dim3(32, NB), dim3(512), 0, stream>>>(Fh, Fl, Pm);
    k_pv<<<dim3(8, 16, NB), dim3(256), 0, stream>>>(cam, Pm, alphap, out);
}